// Round 10
// baseline (13783.008 us; speedup 1.0000x reference)
//
#include <hip/hip_runtime.h>
#include <hip/hip_bf16.h>
#include <hip/hip_cooperative_groups.h>

namespace cg = cooperative_groups;

typedef unsigned short ushort_t;
typedef unsigned int uint32;
typedef __attribute__((ext_vector_type(8))) __bf16 bf16x8;
typedef __attribute__((ext_vector_type(4))) float f32x4;
typedef __attribute__((ext_vector_type(4))) unsigned int u32x4;

#define SEQ_LEN 1024
#define RSLOT 16

#define WPACK_OFF 0ull
#define RING_OFF  (4ull << 20)                     /* 16 slots x 512KB f32 xproj */
#define HX_OFF    (RING_OFF + (8ull << 20))        /* h double buffer 2 x 64KB */
#define HFLG_OFF  (HX_OFF + (128ull << 10))        /* 256 consumer wave flags */
#define XFLG_OFF  (HFLG_OFF + (1ull << 10))        /* 256 producer wave flags */
#define WS_NEED   (XFLG_OFF + (1ull << 10))

__device__ __forceinline__ ushort_t f2bf(float f) {
  unsigned u = __builtin_bit_cast(unsigned, f);
  unsigned r = (u + 0x7fffu + ((u >> 16) & 1u)) >> 16;
  return (ushort_t)r;
}
__device__ __forceinline__ float sigm(float x) {
  float e = __expf(-x);
  return __builtin_amdgcn_rcpf(1.f + e);
}
__device__ __forceinline__ float tanh_fast(float x) {
  float a = fabsf(x);
  float e = __expf(-2.f * a);
  float r = (1.f - e) * __builtin_amdgcn_rcpf(1.f + e);
  return copysignf(r, x);
}
__device__ __forceinline__ uint32 umin2(uint32 a, uint32 b) { return a < b ? a : b; }

__global__ void zero_mem_kernel(u32x4* p) {
  int i = blockIdx.x * blockDim.x + threadIdx.x;
  u32x4 z = {0u, 0u, 0u, 0u};
  p[i] = z;
}

// pack W = [W_i; W_h] frag-major per tile (128 tiles of 4 h-cols):
// col = gate*512 + tile*4 + hcl ; p = hcl<<2|gate ; lane = hi*16+p ;
// k = 32kk+8hi+r ; part = k>>9 ; dst = ((tile*32 + part*16 + kk)*64 + lane)*8 + r
__global__ void pack_w_kernel(const float* __restrict__ Wi, const float* __restrict__ Wh,
                              ushort_t* __restrict__ wp) {
  unsigned e = blockIdx.x * blockDim.x + threadIdx.x;  // 1024*2048
  int k = e >> 11;
  int col = e & 2047;
  float v = (k < 512) ? Wi[(size_t)k * 2048 + col] : Wh[(size_t)(k - 512) * 2048 + col];
  int tile = (col & 511) >> 2;
  int hcl  = col & 3;
  int gate = col >> 9;
  int p = (hcl << 2) | gate;
  int part = k >> 9;
  int kk = (k >> 5) & 15;
  int hi = (k >> 3) & 3;
  int r = k & 7;
  int lane = (hi << 4) | p;
  wp[(size_t)((tile * 32 + part * 16 + kk) * 64 + lane) * 8 + r] = f2bf(v);
}

// ---------------- FAST: producer/consumer wave-specialized LSTM ----------------
// 64 WGs x 512 thr. WG<32: consumer; else producer. Wave wv: bq=wv&3, th=wv>>2.
// pair = wgr*2+th (0..63) -> tiles 2*pair, 2*pair+1 ; pid = wgr*8+wv (0..255).
// Consumer: 32 W_h frags in VGPR; per step: poll(xflg[pid]>=t+1 & all hflg>=t),
//   load 2 ring entries + 16 dense h units (sc), 32 MFMA, cell, store 2 h shorts,
//   drain, hflg[pid]=t+1. Producer: 32 W_i frags in VGPR; per step: load x f32,
//   (t>=R: guard hflg[pid]>=t-R+1), 32 MFMA + bias, sc-store 2 ring entries,
//   drain, xflg[pid]=t+1.
__global__ __launch_bounds__(512, 1) void lstm_fast(
    const float* __restrict__ x, const float* __restrict__ bias,
    const u32x4* __restrict__ wpack, uint32* __restrict__ ring,
    ushort_t* __restrict__ hx, uint32* __restrict__ hflg,
    uint32* __restrict__ xflg, float* __restrict__ out)
{
  const int tid  = threadIdx.x;
  const int lane = tid & 63;
  const int wv   = tid >> 6;
  const int bq   = wv & 3;
  const int th   = wv >> 2;
  const int hi2  = lane >> 4;
  const int lo   = lane & 15;
  const int b    = bq * 16 + lo;

  const bool consumer = (blockIdx.x < 32);
  const int wgr   = consumer ? blockIdx.x : (blockIdx.x - 32);
  const int pair  = wgr * 2 + th;
  const int tileA = pair * 2, tileB = pair * 2 + 1;
  const int pid   = wgr * 8 + wv;
  const int khA   = pair * 8 + hi2;
  const int khB   = khA + 4;

  if (consumer) {
    bf16x8 wA[16], wB[16];
    {
      const u32x4* wa = wpack + ((size_t)tileA * 32 + 16) * 64 + lane;
      const u32x4* wb = wpack + ((size_t)tileB * 32 + 16) * 64 + lane;
#pragma unroll
      for (int kk = 0; kk < 16; ++kk) {
        wA[kk] = __builtin_bit_cast(bf16x8, wa[kk * 64]);
        wB[kk] = __builtin_bit_cast(bf16x8, wb[kk * 64]);
      }
    }
    const int hoffA = ((bq * 16 + (khA >> 5)) * 64 + ((khA >> 3) & 3) * 16 + lo) * 8 + (khA & 7);
    const int hoffB = ((bq * 16 + (khB >> 5)) * 64 + ((khB >> 3) & 3) * 16 + lo) * 8 + (khB & 7);

    float cA = 0.f, cB = 0.f, hA = 0.f, hB = 0.f;

    for (int t = 0; t < SEQ_LEN; ++t) {
      // ---- poll: producer t done + (t>0) all consumers t-1 done ----
      {
        const uint32* xfp = xflg + pid;
        const u32x4* hfp = (const u32x4*)hflg + lane;
        const uint32 need_x = (uint32)(t + 1);
        const uint32 need_h = (uint32)t;
        while (true) {
          uint32 xf; u32x4 hf;
          asm volatile("global_load_dword %0, %2, off sc0 sc1\n\t"
                       "global_load_dwordx4 %1, %3, off sc0 sc1\n\t"
                       "s_waitcnt vmcnt(0)"
                       : "=&v"(xf), "=&v"(hf) : "v"(xfp), "v"(hfp) : "memory");
          __builtin_amdgcn_sched_barrier(0);
          uint32 mn = umin2(umin2(hf[0], hf[1]), umin2(hf[2], hf[3]));
          bool ok = (xf >= need_x) && (t == 0 || mn >= need_h);
          if (__all(ok)) break;
        }
      }
      // ---- issue ring(xproj) + h loads, one round trip ----
      u32x4 xpAu, xpBu;
      {
        const u32x4* rbase = (const u32x4*)ring + ((size_t)(t & (RSLOT - 1)) * 128) * 256;
        const u32x4* rpA = rbase + ((size_t)tileA * 4 + bq) * 64 + lane;
        const u32x4* rpB = rbase + ((size_t)tileB * 4 + bq) * 64 + lane;
        asm volatile("global_load_dwordx4 %0, %1, off sc0 sc1"
                     : "=v"(xpAu) : "v"(rpA) : "memory");
        asm volatile("global_load_dwordx4 %0, %1, off sc0 sc1"
                     : "=v"(xpBu) : "v"(rpB) : "memory");
      }
      f32x4 gA, gB;
      if (t == 0) {
        asm volatile("s_waitcnt vmcnt(0)" ::: "memory");
        __builtin_amdgcn_sched_barrier(0);
        gA = __builtin_bit_cast(f32x4, xpAu);
        gB = __builtin_bit_cast(f32x4, xpBu);
      } else {
        u32x4 hreg[16];
        const u32x4* hr = (const u32x4*)(hx + (size_t)(t & 1) * 32768) + bq * 1024 + lane;
#pragma unroll
        for (int kk = 0; kk < 16; ++kk)
          asm volatile("global_load_dwordx4 %0, %1, off sc0 sc1"
                       : "=v"(hreg[kk]) : "v"(hr + kk * 64) : "memory");
        asm volatile("s_waitcnt vmcnt(0)" ::: "memory");
        __builtin_amdgcn_sched_barrier(0);
        f32x4 aA0 = __builtin_bit_cast(f32x4, xpAu);
        f32x4 aB0 = __builtin_bit_cast(f32x4, xpBu);
        f32x4 aA1 = {0.f, 0.f, 0.f, 0.f};
        f32x4 aB1 = {0.f, 0.f, 0.f, 0.f};
#pragma unroll
        for (int kk = 0; kk < 16; kk += 2) {
          bf16x8 h0 = __builtin_bit_cast(bf16x8, hreg[kk]);
          bf16x8 h1 = __builtin_bit_cast(bf16x8, hreg[kk + 1]);
          aA0 = __builtin_amdgcn_mfma_f32_16x16x32_bf16(wA[kk], h0, aA0, 0, 0, 0);
          aB0 = __builtin_amdgcn_mfma_f32_16x16x32_bf16(wB[kk], h0, aB0, 0, 0, 0);
          aA1 = __builtin_amdgcn_mfma_f32_16x16x32_bf16(wA[kk + 1], h1, aA1, 0, 0, 0);
          aB1 = __builtin_amdgcn_mfma_f32_16x16x32_bf16(wB[kk + 1], h1, aB1, 0, 0, 0);
        }
        gA = aA0 + aA1;
        gB = aB0 + aB1;
      }
      // ---- cell update (2 cells per lane) ----
      {
        float it = sigm(gA[0]), ft = sigm(gA[1]), ot = sigm(gA[3]), gt = tanh_fast(gA[2]);
        cA = ft * cA + it * gt;
        hA = ot * tanh_fast(cA);
      }
      {
        float it = sigm(gB[0]), ft = sigm(gB[1]), ot = sigm(gB[3]), gt = tanh_fast(gB[2]);
        cB = ft * cB + it * gt;
        hB = ot * tanh_fast(cB);
      }
      if (t < SEQ_LEN - 1) {
        ushort_t* hw = hx + (size_t)((t + 1) & 1) * 32768;
        uint32 vA = f2bf(hA), vB = f2bf(hB);
        asm volatile("global_store_short %0, %1, off sc0 sc1"
                     :: "v"(hw + hoffA), "v"(vA) : "memory");
        asm volatile("global_store_short %0, %1, off sc0 sc1"
                     :: "v"(hw + hoffB), "v"(vB) : "memory");
        asm volatile("s_waitcnt vmcnt(0)" ::: "memory");
        __builtin_amdgcn_sched_barrier(0);
        if (lane == 0) {
          uint32* fp = hflg + pid;
          uint32 val = (uint32)(t + 1);
          asm volatile("global_store_dword %0, %1, off sc0 sc1"
                       :: "v"(fp), "v"(val) : "memory");
        }
      }
    }
    out[(size_t)b * 512 + khA] = hA;
    out[(size_t)b * 512 + khB] = hB;
    out[32768 + (size_t)b * 512 + khA] = cA;
    out[32768 + (size_t)b * 512 + khB] = cB;
  } else {
    // ---------------- producer ----------------
    bf16x8 wA[16], wB[16];
    {
      const u32x4* wa = wpack + ((size_t)tileA * 32) * 64 + lane;
      const u32x4* wb = wpack + ((size_t)tileB * 32) * 64 + lane;
#pragma unroll
      for (int kk = 0; kk < 16; ++kk) {
        wA[kk] = __builtin_bit_cast(bf16x8, wa[kk * 64]);
        wB[kk] = __builtin_bit_cast(bf16x8, wb[kk * 64]);
      }
    }
    f32x4 biaA = {bias[0 * 512 + khA], bias[1 * 512 + khA],
                  bias[2 * 512 + khA], bias[3 * 512 + khA]};
    f32x4 biaB = {bias[0 * 512 + khB], bias[1 * 512 + khB],
                  bias[2 * 512 + khB], bias[3 * 512 + khB]};

    for (int t = 0; t < SEQ_LEN; ++t) {
      // ---- load & convert x (plain cached; off critical path) ----
      bf16x8 xv[16];
      {
        const float* xr = x + ((size_t)b * SEQ_LEN + t) * 512 + (hi2 << 3);
#pragma unroll
        for (int kk = 0; kk < 16; ++kk) {
          f32x4 f0 = *(const f32x4*)(xr + (kk << 5));
          f32x4 f1 = *(const f32x4*)(xr + (kk << 5) + 4);
          u32x4 v;
          v[0] = f2bf(f0[0]) | ((uint32)f2bf(f0[1]) << 16);
          v[1] = f2bf(f0[2]) | ((uint32)f2bf(f0[3]) << 16);
          v[2] = f2bf(f1[0]) | ((uint32)f2bf(f1[1]) << 16);
          v[3] = f2bf(f1[2]) | ((uint32)f2bf(f1[3]) << 16);
          xv[kk] = __builtin_bit_cast(bf16x8, v);
        }
      }
      // ---- ring reuse guard ----
      if (t >= RSLOT) {
        const uint32* gp = hflg + pid;
        const uint32 need = (uint32)(t - RSLOT + 1);
        while (true) {
          uint32 v;
          asm volatile("global_load_dword %0, %1, off sc0 sc1\n\ts_waitcnt vmcnt(0)"
                       : "=v"(v) : "v"(gp) : "memory");
          if (__all(v >= need)) break;
        }
        __builtin_amdgcn_sched_barrier(0);
      }
      // ---- x-projection MFMAs ----
      f32x4 aA0 = biaA, aB0 = biaB;
      f32x4 aA1 = {0.f, 0.f, 0.f, 0.f};
      f32x4 aB1 = {0.f, 0.f, 0.f, 0.f};
#pragma unroll
      for (int kk = 0; kk < 16; kk += 2) {
        aA0 = __builtin_amdgcn_mfma_f32_16x16x32_bf16(wA[kk], xv[kk], aA0, 0, 0, 0);
        aB0 = __builtin_amdgcn_mfma_f32_16x16x32_bf16(wB[kk], xv[kk], aB0, 0, 0, 0);
        aA1 = __builtin_amdgcn_mfma_f32_16x16x32_bf16(wA[kk + 1], xv[kk + 1], aA1, 0, 0, 0);
        aB1 = __builtin_amdgcn_mfma_f32_16x16x32_bf16(wB[kk + 1], xv[kk + 1], aB1, 0, 0, 0);
      }
      u32x4 rA = __builtin_bit_cast(u32x4, aA0 + aA1);
      u32x4 rB = __builtin_bit_cast(u32x4, aB0 + aB1);
      {
        u32x4* rbase = (u32x4*)ring + ((size_t)(t & (RSLOT - 1)) * 128) * 256;
        u32x4* rpA = rbase + ((size_t)tileA * 4 + bq) * 64 + lane;
        u32x4* rpB = rbase + ((size_t)tileB * 4 + bq) * 64 + lane;
        asm volatile("global_store_dwordx4 %0, %1, off sc0 sc1"
                     :: "v"(rpA), "v"(rA) : "memory");
        asm volatile("global_store_dwordx4 %0, %1, off sc0 sc1"
                     :: "v"(rpB), "v"(rB) : "memory");
        asm volatile("s_waitcnt vmcnt(0)" ::: "memory");
        __builtin_amdgcn_sched_barrier(0);
        if (lane == 0) {
          uint32* fp = xflg + pid;
          uint32 val = (uint32)(t + 1);
          asm volatile("global_store_dword %0, %1, off sc0 sc1"
                       :: "v"(fp), "v"(val) : "memory");
        }
      }
    }
  }
}

// ---------------- SLOW fallback: R9's proven cooperative kernel ----------------
__global__ void __launch_bounds__(256, 1)
lstm_slow(const float* __restrict__ x, const float* __restrict__ Wi,
          const float* __restrict__ Wh, const float* __restrict__ bias,
          ushort_t* hbuf, float* out)
{
  __shared__ u32x4 lA[8192];
  const int tid  = threadIdx.x;
  const int wg   = blockIdx.x;
  const int lane = tid & 63;
  const int wv   = tid >> 6;
  const int hi2  = lane >> 4;
  const int lo   = lane & 15;
  const int b    = (wv << 4) | lo;

  for (int uu = tid; uu < 8192; uu += 256) {
    int ln = uu & 63, tau = (uu >> 6) & 3, kk = uu >> 8;
    int uhi = ln >> 4, p = ln & 15;
    int gate = p & 3, hcl = p >> 2;
    int col = gate * 512 + (wg << 4) + tau * 4 + hcl;
    ushort_t tmp[8];
#pragma unroll
    for (int r = 0; r < 8; ++r) {
      int k = (kk << 5) + (uhi << 3) + r;
      float f = (k < 512) ? Wi[(size_t)k * 2048 + col] : Wh[(size_t)(k - 512) * 2048 + col];
      tmp[r] = f2bf(f);
    }
    u32x4 v;
    v[0] = tmp[0] | ((uint32)tmp[1] << 16);
    v[1] = tmp[2] | ((uint32)tmp[3] << 16);
    v[2] = tmp[4] | ((uint32)tmp[5] << 16);
    v[3] = tmp[6] | ((uint32)tmp[7] << 16);
    lA[uu] = v;
  }
  __syncthreads();

  int kh[4], uoff[4];
  float bia[4][4];
#pragma unroll
  for (int tau = 0; tau < 4; ++tau) {
    int k = (wg << 4) + tau * 4 + hi2;
    kh[tau] = k;
    uoff[tau] = ((wv * 1024 + (k >> 5) * 64 + ((k >> 3) & 3) * 16 + lo) << 3) + (k & 7);
#pragma unroll
    for (int g = 0; g < 4; ++g) bia[tau][g] = bias[g * 512 + k];
  }

  float c[4] = {0.f, 0.f, 0.f, 0.f};
  float hn[4] = {0.f, 0.f, 0.f, 0.f};

  for (int t = 0; t < SEQ_LEN; ++t) {
    f32x4 ax0 = {bia[0][0], bia[0][1], bia[0][2], bia[0][3]};
    f32x4 ax1 = {bia[1][0], bia[1][1], bia[1][2], bia[1][3]};
    f32x4 ax2 = {bia[2][0], bia[2][1], bia[2][2], bia[2][3]};
    f32x4 ax3 = {bia[3][0], bia[3][1], bia[3][2], bia[3][3]};
#pragma unroll
    for (int kk = 0; kk < 16; ++kk) {
      const float* xr = x + ((size_t)b * SEQ_LEN + t) * 512 + (kk << 5) + (hi2 << 3);
      f32x4 f0 = *(const f32x4*)(xr);
      f32x4 f1 = *(const f32x4*)(xr + 4);
      u32x4 v;
      v[0] = f2bf(f0[0]) | ((uint32)f2bf(f0[1]) << 16);
      v[1] = f2bf(f0[2]) | ((uint32)f2bf(f0[3]) << 16);
      v[2] = f2bf(f1[0]) | ((uint32)f2bf(f1[1]) << 16);
      v[3] = f2bf(f1[2]) | ((uint32)f2bf(f1[3]) << 16);
      bf16x8 xv = __builtin_bit_cast(bf16x8, v);
      ax0 = __builtin_amdgcn_mfma_f32_16x16x32_bf16(
              __builtin_bit_cast(bf16x8, lA[(kk * 4 + 0) * 64 + lane]), xv, ax0, 0, 0, 0);
      ax1 = __builtin_amdgcn_mfma_f32_16x16x32_bf16(
              __builtin_bit_cast(bf16x8, lA[(kk * 4 + 1) * 64 + lane]), xv, ax1, 0, 0, 0);
      ax2 = __builtin_amdgcn_mfma_f32_16x16x32_bf16(
              __builtin_bit_cast(bf16x8, lA[(kk * 4 + 2) * 64 + lane]), xv, ax2, 0, 0, 0);
      ax3 = __builtin_amdgcn_mfma_f32_16x16x32_bf16(
              __builtin_bit_cast(bf16x8, lA[(kk * 4 + 3) * 64 + lane]), xv, ax3, 0, 0, 0);
    }

    if (t > 0) {
      const u32x4* hr = (const u32x4*)(hbuf + (size_t)(t & 1) * 32768) + wv * 1024 + lane;
      u32x4 hreg[16];
#pragma unroll
      for (int kk = 0; kk < 16; ++kk) hreg[kk] = hr[kk * 64];
#pragma unroll
      for (int kk = 0; kk < 16; ++kk) {
        bf16x8 hv = __builtin_bit_cast(bf16x8, hreg[kk]);
        ax0 = __builtin_amdgcn_mfma_f32_16x16x32_bf16(
                __builtin_bit_cast(bf16x8, lA[((16 + kk) * 4 + 0) * 64 + lane]), hv, ax0, 0, 0, 0);
        ax1 = __builtin_amdgcn_mfma_f32_16x16x32_bf16(
                __builtin_bit_cast(bf16x8, lA[((16 + kk) * 4 + 1) * 64 + lane]), hv, ax1, 0, 0, 0);
        ax2 = __builtin_amdgcn_mfma_f32_16x16x32_bf16(
                __builtin_bit_cast(bf16x8, lA[((16 + kk) * 4 + 2) * 64 + lane]), hv, ax2, 0, 0, 0);
        ax3 = __builtin_amdgcn_mfma_f32_16x16x32_bf16(
                __builtin_bit_cast(bf16x8, lA[((16 + kk) * 4 + 3) * 64 + lane]), hv, ax3, 0, 0, 0);
      }
    }

    f32x4 axv[4] = {ax0, ax1, ax2, ax3};
#pragma unroll
    for (int tau = 0; tau < 4; ++tau) {
      float gi = axv[tau][0], gf = axv[tau][1], gg = axv[tau][2], go = axv[tau][3];
      float it = sigm(gi), ft = sigm(gf), ot = sigm(go), gt = tanh_fast(gg);
      c[tau] = ft * c[tau] + it * gt;
      hn[tau] = ot * tanh_fast(c[tau]);
    }

    if (t < SEQ_LEN - 1) {
      ushort_t* hw = hbuf + (size_t)((t + 1) & 1) * 32768;
#pragma unroll
      for (int tau = 0; tau < 4; ++tau) hw[uoff[tau]] = f2bf(hn[tau]);
      __threadfence();
      cg::this_grid().sync();
      __threadfence();
    } else {
      __threadfence();
      cg::this_grid().sync();
    }
  }

#pragma unroll
  for (int tau = 0; tau < 4; ++tau) {
    out[(size_t)b * 512 + kh[tau]] = hn[tau];
    out[32768 + (size_t)b * 512 + kh[tau]] = c[tau];
  }
}

extern "C" void kernel_launch(void* const* d_in, const int* in_sizes, int n_in,
                              void* d_out, int out_size, void* d_ws, size_t ws_size,
                              hipStream_t stream) {
  const float* x    = (const float*)d_in[0];
  const float* Wi   = (const float*)d_in[1];
  const float* Wh   = (const float*)d_in[2];
  const float* bias = (const float*)d_in[3];
  float* out = (float*)d_out;

  bool fast = (d_ws != nullptr) && (ws_size >= WS_NEED);

  if (fast) {
    const u32x4* wpack = (const u32x4*)((char*)d_ws + WPACK_OFF);
    uint32* ring  = (uint32*)((char*)d_ws + RING_OFF);
    ushort_t* hx  = (ushort_t*)((char*)d_ws + HX_OFF);
    uint32* hflg  = (uint32*)((char*)d_ws + HFLG_OFF);
    uint32* xflg  = (uint32*)((char*)d_ws + XFLG_OFF);

    zero_mem_kernel<<<1, 128, 0, stream>>>((u32x4*)((char*)d_ws + HFLG_OFF)); // 2KB flags
    pack_w_kernel<<<8192, 256, 0, stream>>>(Wi, Wh, (ushort_t*)((char*)d_ws + WPACK_OFF));

    lstm_fast<<<dim3(64), dim3(512), 0, stream>>>(
        x, bias, wpack, ring, hx, hflg, xflg, out);
  } else {
    ushort_t* hbuf = (ushort_t*)d_out;   // two 64KB slots inside 256KB d_out

    void* args[] = {(void*)&x, (void*)&Wi, (void*)&Wh, (void*)&bias,
                    (void*)&hbuf, (void*)&out};
    void (*kfn)(const float*, const float*, const float*, const float*,
                ushort_t*, float*) = lstm_slow;
    hipLaunchCooperativeKernel(reinterpret_cast<void*>(kfn), dim3(32), dim3(256),
                               args, 0, stream);
  }
}

// Round 11
// 3510.800 us; speedup vs baseline: 3.9259x; 3.9259x over previous
//
#include <hip/hip_runtime.h>
#include <hip/hip_bf16.h>
#include <hip/hip_cooperative_groups.h>

namespace cg = cooperative_groups;

typedef unsigned short ushort_t;
typedef unsigned int uint32;
typedef __attribute__((ext_vector_type(8))) __bf16 bf16x8;
typedef __attribute__((ext_vector_type(4))) float f32x4;
typedef __attribute__((ext_vector_type(4))) unsigned int u32x4;

#define SEQ_LEN 1024

#define XPACK_BYTES (64ull << 20)                /* dense per-bq x frags (R9 layout) */
#define WPACK_OFF   XPACK_BYTES                  /* 4MB tile-frag-major W (R10 layout) */
#define HX_OFF      (WPACK_OFF + (4ull << 20))   /* h double buffer 2 x 64KB, dense */
#define FLG_OFF     (HX_OFF + (128ull << 10))    /* 256 flags [bq][wg], zeroed 4KB */
#define WS_NEED     (FLG_OFF + (4ull << 10))

__device__ __forceinline__ ushort_t f2bf(float f) {
  unsigned u = __builtin_bit_cast(unsigned, f);
  unsigned r = (u + 0x7fffu + ((u >> 16) & 1u)) >> 16;
  return (ushort_t)r;
}
__device__ __forceinline__ float sigm(float x) {
  float e = __expf(-x);
  return __builtin_amdgcn_rcpf(1.f + e);
}
__device__ __forceinline__ float tanh_fast(float x) {
  float a = fabsf(x);
  float e = __expf(-2.f * a);
  float r = (1.f - e) * __builtin_amdgcn_rcpf(1.f + e);
  return copysignf(r, x);
}

__global__ void zero_mem_kernel(u32x4* p) {
  int i = blockIdx.x * blockDim.x + threadIdx.x;
  u32x4 z = {0u, 0u, 0u, 0u};
  p[i] = z;
}

// pack x f32 -> bf16 dense per-bq frag layout (PROVEN in R9):
// unit(t,bq,kk,lane) = t*4096 + bq*1024 + kk*64 + lane ;
// holds x[b=bq*16+(lane&15)][t][k=kk*32+(lane>>4)*8+r], r=0..7
__global__ void pack_x_kernel(const float* __restrict__ x, u32x4* __restrict__ xp) {
  unsigned u = blockIdx.x * blockDim.x + threadIdx.x;   // 4M units
  int lane = u & 63;
  int kk   = (u >> 6) & 15;
  int bq   = (u >> 10) & 3;
  int t    = u >> 12;
  int hi2 = lane >> 4, lo = lane & 15;
  int b  = bq * 16 + lo;
  int k0 = kk * 32 + hi2 * 8;
  const float* src = x + ((size_t)b * SEQ_LEN + t) * 512 + k0;
  f32x4 f0 = *(const f32x4*)(src);
  f32x4 f1 = *(const f32x4*)(src + 4);
  u32x4 o;
  o[0] = f2bf(f0[0]) | ((uint32)f2bf(f0[1]) << 16);
  o[1] = f2bf(f0[2]) | ((uint32)f2bf(f0[3]) << 16);
  o[2] = f2bf(f1[0]) | ((uint32)f2bf(f1[1]) << 16);
  o[3] = f2bf(f1[2]) | ((uint32)f2bf(f1[3]) << 16);
  xp[u] = o;
}

// pack W = [W_i; W_h] tile-frag-major (PROVEN in R10): 128 tiles of 4 h-cols;
// col = gate*512 + tile*4 + hcl ; lane = hi*16 + (hcl<<2|gate) ; k = 32kk+8hi+r ;
// part = k>>9 ; dst u32x4 unit = (tile*32 + part*16 + kk)*64 + lane
__global__ void pack_w_kernel(const float* __restrict__ Wi, const float* __restrict__ Wh,
                              ushort_t* __restrict__ wp) {
  unsigned e = blockIdx.x * blockDim.x + threadIdx.x;  // 1024*2048
  int k = e >> 11;
  int col = e & 2047;
  float v = (k < 512) ? Wi[(size_t)k * 2048 + col] : Wh[(size_t)(k - 512) * 2048 + col];
  int tile = (col & 511) >> 2;
  int hcl  = col & 3;
  int gate = col >> 9;
  int p = (hcl << 2) | gate;
  int part = k >> 9;
  int kk = (k >> 5) & 15;
  int hi = (k >> 3) & 3;
  int r = k & 7;
  int lane = (hi << 4) | p;
  wp[(size_t)((tile * 32 + part * 16 + kk) * 64 + lane) * 8 + r] = f2bf(v);
}

// ---------------- FAST: intra-WG wave-specialized LSTM ----------------
// 64 WGs x 512 thr. Waves 0-3: recurrent (bq=wv). Waves 4-7: input (bq=wv-4).
// Recurrent: W_h (tiles 2wg,2wg+1, part1) PINNED in 128 VGPRs; per step:
//   poll 64 same-bq flags -> dense 16KB sc h-load -> 32 reg MFMA -> cell ->
//   2 short stores -> drain -> flag[bq*64+wg]=t+1.
// Input: W_i in LDS; computes xproj(t+1)+bias from xpack into LDS double
//   buffer xbuf[(t+1)&1][tt][bq][lane] (f32x4 = 4 gates of h-col wg*8+tt*4+hi2,
//   batch bq*16+lo -- same lane mapping as recurrent consumer).
// One __syncthreads per step orders the LDS double buffer.
__global__ __launch_bounds__(512, 1) void lstm_fast(
    const u32x4* __restrict__ xpack, const u32x4* __restrict__ wpack,
    const float* __restrict__ bias, ushort_t* __restrict__ hx,
    uint32* __restrict__ flags, float* __restrict__ out)
{
  __shared__ u32x4 wiL[2048];            // 32KB: W_i frags [(kk*2+tt)*64 + lane]
  __shared__ f32x4 xbuf[2][2][4][64];    // 16KB: [buf][tt][bq][lane]

  const int tid  = threadIdx.x;
  const int wg   = blockIdx.x;
  const int lane = tid & 63;
  const int wv   = tid >> 6;
  const bool rec = (wv < 4);
  const int bq   = wv & 3;
  const int hi2  = lane >> 4;
  const int lo   = lane & 15;
  const int b    = bq * 16 + lo;

  // stage W_i (part 0 of tiles 2wg, 2wg+1) into LDS -- all 512 threads
  for (int i = tid; i < 2048; i += 512) {
    int ln = i & 63, tt = (i >> 6) & 1, kk = i >> 7;
    wiL[i] = wpack[(size_t)(((2 * wg + tt) * 32 + kk) * 64) + ln];
  }

  // recurrent waves: W_h (part 1) into VGPRs, PINNED so it cannot remat/spill-to-global
  bf16x8 wh0[16], wh1[16];
  if (rec) {
    const u32x4* wsA = wpack + (size_t)(((2 * wg + 0) * 32 + 16) * 64) + lane;
    const u32x4* wsB = wpack + (size_t)(((2 * wg + 1) * 32 + 16) * 64) + lane;
#pragma unroll
    for (int kk = 0; kk < 16; ++kk) {
      u32x4 a = wsA[kk * 64];
      u32x4 c = wsB[kk * 64];
      asm volatile("" : "+v"(a));
      asm volatile("" : "+v"(c));
      wh0[kk] = __builtin_bit_cast(bf16x8, a);
      wh1[kk] = __builtin_bit_cast(bf16x8, c);
    }
  }
  __syncthreads();   // wiL ready

  const int kh0 = wg * 8 + hi2;
  const int kh1 = kh0 + 4;

  // input waves: bias vectors + preloop xproj(0) -> xbuf[0]
  f32x4 bia0, bia1;
  if (!rec) {
    bia0 = f32x4{bias[0 * 512 + kh0], bias[1 * 512 + kh0],
                 bias[2 * 512 + kh0], bias[3 * 512 + kh0]};
    bia1 = f32x4{bias[0 * 512 + kh1], bias[1 * 512 + kh1],
                 bias[2 * 512 + kh1], bias[3 * 512 + kh1]};
    f32x4 a0 = bia0, a1 = bia1;
    const u32x4* xb = xpack + bq * 1024 + lane;   // t = 0
#pragma unroll
    for (int kk = 0; kk < 16; ++kk) {
      bf16x8 xv = __builtin_bit_cast(bf16x8, xb[kk * 64]);
      a0 = __builtin_amdgcn_mfma_f32_16x16x32_bf16(
             __builtin_bit_cast(bf16x8, wiL[(kk * 2 + 0) * 64 + lane]), xv, a0, 0, 0, 0);
      a1 = __builtin_amdgcn_mfma_f32_16x16x32_bf16(
             __builtin_bit_cast(bf16x8, wiL[(kk * 2 + 1) * 64 + lane]), xv, a1, 0, 0, 0);
    }
    xbuf[0][0][bq][lane] = a0;
    xbuf[0][1][bq][lane] = a1;
  }

  // dense h store offsets (ushort units within one 64KB slot)
  const int hoff0 = bq * 8192 + (((kh0 >> 5) * 64 + ((kh0 >> 3) & 3) * 16 + lo) << 3) + (kh0 & 7);
  const int hoff1 = hoff0 + 4;   // kh1 = kh0+4 lands in the same 16B unit, r+4

  float c0 = 0.f, c1 = 0.f, h0v = 0.f, h1v = 0.f;

  for (int t = 0; t < SEQ_LEN; ++t) {
    __syncthreads();   // xbuf[t&1] ready; xbuf[(t+1)&1] free to overwrite

    if (rec) {
      // ---- wait for h_t from the 64 same-bq producer waves ----
      if (t > 0) {
        const uint32* fp = flags + bq * 64 + lane;
        const uint32 tt = (uint32)t;
        while (true) {
          uint32 v;
          asm volatile("global_load_dword %0, %1, off sc0 sc1\n\ts_waitcnt vmcnt(0)"
                       : "=v"(v) : "v"(fp) : "memory");
          if (__all(v >= tt)) break;
        }
        __builtin_amdgcn_sched_barrier(0);
      }
      // ---- gate partials from input waves (includes bias) ----
      f32x4 g0 = xbuf[t & 1][0][bq][lane];
      f32x4 g1 = xbuf[t & 1][1][bq][lane];

      if (t > 0) {
        // ---- dense 16KB sc h-load ----
        const u32x4* hr = (const u32x4*)(hx + (size_t)(t & 1) * 32768) + bq * 1024 + lane;
        u32x4 hreg[16];
#pragma unroll
        for (int kk = 0; kk < 16; ++kk)
          asm volatile("global_load_dwordx4 %0, %1, off sc0 sc1"
                       : "=v"(hreg[kk]) : "v"(hr + kk * 64) : "memory");
        asm volatile("s_waitcnt vmcnt(0)" ::: "memory");
        __builtin_amdgcn_sched_barrier(0);
        // ---- 32 register-only MFMAs, 4 independent acc chains ----
        f32x4 a00 = g0, a10 = g1;
        f32x4 a01 = {0.f, 0.f, 0.f, 0.f};
        f32x4 a11 = {0.f, 0.f, 0.f, 0.f};
#pragma unroll
        for (int kk = 0; kk < 16; kk += 2) {
          bf16x8 hv0 = __builtin_bit_cast(bf16x8, hreg[kk]);
          bf16x8 hv1 = __builtin_bit_cast(bf16x8, hreg[kk + 1]);
          a00 = __builtin_amdgcn_mfma_f32_16x16x32_bf16(wh0[kk], hv0, a00, 0, 0, 0);
          a10 = __builtin_amdgcn_mfma_f32_16x16x32_bf16(wh1[kk], hv0, a10, 0, 0, 0);
          a01 = __builtin_amdgcn_mfma_f32_16x16x32_bf16(wh0[kk + 1], hv1, a01, 0, 0, 0);
          a11 = __builtin_amdgcn_mfma_f32_16x16x32_bf16(wh1[kk + 1], hv1, a11, 0, 0, 0);
        }
        g0 = a00 + a01;
        g1 = a10 + a11;
      }
      // ---- cell update (2 cells per lane) ----
      {
        float it = sigm(g0[0]), ft = sigm(g0[1]), ot = sigm(g0[3]), gt = tanh_fast(g0[2]);
        c0 = ft * c0 + it * gt;
        h0v = ot * tanh_fast(c0);
      }
      {
        float it = sigm(g1[0]), ft = sigm(g1[1]), ot = sigm(g1[3]), gt = tanh_fast(g1[2]);
        c1 = ft * c1 + it * gt;
        h1v = ot * tanh_fast(c1);
      }
      // ---- publish h(t+1): 2 sc stores -> drain -> flag ----
      if (t < SEQ_LEN - 1) {
        ushort_t* hw = hx + (size_t)((t + 1) & 1) * 32768;
        uint32 v0 = f2bf(h0v), v1 = f2bf(h1v);
        asm volatile("global_store_short %0, %1, off sc0 sc1"
                     :: "v"(hw + hoff0), "v"(v0) : "memory");
        asm volatile("global_store_short %0, %1, off sc0 sc1"
                     :: "v"(hw + hoff1), "v"(v1) : "memory");
        asm volatile("s_waitcnt vmcnt(0)" ::: "memory");
        __builtin_amdgcn_sched_barrier(0);
        if (lane == 0) {
          uint32* fp = flags + bq * 64 + wg;
          uint32 val = (uint32)(t + 1);
          asm volatile("global_store_dword %0, %1, off sc0 sc1"
                       :: "v"(fp), "v"(val) : "memory");
        }
      }
    } else {
      // ---- input waves: xproj(t+1) one step ahead ----
      if (t + 1 < SEQ_LEN) {
        const int tn = t + 1;
        f32x4 a0 = bia0, a1 = bia1;
        const u32x4* xb = xpack + (size_t)tn * 4096 + bq * 1024 + lane;
#pragma unroll
        for (int kk = 0; kk < 16; ++kk) {
          bf16x8 xv = __builtin_bit_cast(bf16x8, xb[kk * 64]);
          a0 = __builtin_amdgcn_mfma_f32_16x16x32_bf16(
                 __builtin_bit_cast(bf16x8, wiL[(kk * 2 + 0) * 64 + lane]), xv, a0, 0, 0, 0);
          a1 = __builtin_amdgcn_mfma_f32_16x16x32_bf16(
                 __builtin_bit_cast(bf16x8, wiL[(kk * 2 + 1) * 64 + lane]), xv, a1, 0, 0, 0);
        }
        xbuf[tn & 1][0][bq][lane] = a0;
        xbuf[tn & 1][1][bq][lane] = a1;
      }
    }
  }

  if (rec) {
    out[(size_t)b * 512 + kh0] = h0v;
    out[(size_t)b * 512 + kh1] = h1v;
    out[32768 + (size_t)b * 512 + kh0] = c0;
    out[32768 + (size_t)b * 512 + kh1] = c1;
  }
}

// ---------------- SLOW fallback: proven cooperative kernel (R9 structure) ----------------
__global__ void __launch_bounds__(256, 1)
lstm_slow(const float* __restrict__ x, const float* __restrict__ Wi,
          const float* __restrict__ Wh, const float* __restrict__ bias,
          ushort_t* hbuf, float* out)
{
  __shared__ u32x4 lA[8192];
  const int tid  = threadIdx.x;
  const int wg   = blockIdx.x;
  const int lane = tid & 63;
  const int wv   = tid >> 6;
  const int hi2  = lane >> 4;
  const int lo   = lane & 15;
  const int b    = (wv << 4) | lo;

  for (int uu = tid; uu < 8192; uu += 256) {
    int ln = uu & 63, tau = (uu >> 6) & 3, kk = uu >> 8;
    int uhi = ln >> 4, p = ln & 15;
    int gate = p & 3, hcl = p >> 2;
    int col = gate * 512 + (wg << 4) + tau * 4 + hcl;
    ushort_t tmp[8];
#pragma unroll
    for (int r = 0; r < 8; ++r) {
      int k = (kk << 5) + (uhi << 3) + r;
      float f = (k < 512) ? Wi[(size_t)k * 2048 + col] : Wh[(size_t)(k - 512) * 2048 + col];
      tmp[r] = f2bf(f);
    }
    u32x4 v;
    v[0] = tmp[0] | ((uint32)tmp[1] << 16);
    v[1] = tmp[2] | ((uint32)tmp[3] << 16);
    v[2] = tmp[4] | ((uint32)tmp[5] << 16);
    v[3] = tmp[6] | ((uint32)tmp[7] << 16);
    lA[uu] = v;
  }
  __syncthreads();

  int kh[4], uoff[4];
  float bia[4][4];
#pragma unroll
  for (int tau = 0; tau < 4; ++tau) {
    int k = (wg << 4) + tau * 4 + hi2;
    kh[tau] = k;
    uoff[tau] = ((wv * 1024 + (k >> 5) * 64 + ((k >> 3) & 3) * 16 + lo) << 3) + (k & 7);
#pragma unroll
    for (int g = 0; g < 4; ++g) bia[tau][g] = bias[g * 512 + k];
  }

  float c[4] = {0.f, 0.f, 0.f, 0.f};
  float hn[4] = {0.f, 0.f, 0.f, 0.f};

  for (int t = 0; t < SEQ_LEN; ++t) {
    f32x4 ax0 = {bia[0][0], bia[0][1], bia[0][2], bia[0][3]};
    f32x4 ax1 = {bia[1][0], bia[1][1], bia[1][2], bia[1][3]};
    f32x4 ax2 = {bia[2][0], bia[2][1], bia[2][2], bia[2][3]};
    f32x4 ax3 = {bia[3][0], bia[3][1], bia[3][2], bia[3][3]};
#pragma unroll
    for (int kk = 0; kk < 16; ++kk) {
      const float* xr = x + ((size_t)b * SEQ_LEN + t) * 512 + (kk << 5) + (hi2 << 3);
      f32x4 f0 = *(const f32x4*)(xr);
      f32x4 f1 = *(const f32x4*)(xr + 4);
      u32x4 v;
      v[0] = f2bf(f0[0]) | ((uint32)f2bf(f0[1]) << 16);
      v[1] = f2bf(f0[2]) | ((uint32)f2bf(f0[3]) << 16);
      v[2] = f2bf(f1[0]) | ((uint32)f2bf(f1[1]) << 16);
      v[3] = f2bf(f1[2]) | ((uint32)f2bf(f1[3]) << 16);
      bf16x8 xv = __builtin_bit_cast(bf16x8, v);
      ax0 = __builtin_amdgcn_mfma_f32_16x16x32_bf16(
              __builtin_bit_cast(bf16x8, lA[(kk * 4 + 0) * 64 + lane]), xv, ax0, 0, 0, 0);
      ax1 = __builtin_amdgcn_mfma_f32_16x16x32_bf16(
              __builtin_bit_cast(bf16x8, lA[(kk * 4 + 1) * 64 + lane]), xv, ax1, 0, 0, 0);
      ax2 = __builtin_amdgcn_mfma_f32_16x16x32_bf16(
              __builtin_bit_cast(bf16x8, lA[(kk * 4 + 2) * 64 + lane]), xv, ax2, 0, 0, 0);
      ax3 = __builtin_amdgcn_mfma_f32_16x16x32_bf16(
              __builtin_bit_cast(bf16x8, lA[(kk * 4 + 3) * 64 + lane]), xv, ax3, 0, 0, 0);
    }

    if (t > 0) {
      const u32x4* hr = (const u32x4*)(hbuf + (size_t)(t & 1) * 32768) + wv * 1024 + lane;
      u32x4 hreg[16];
#pragma unroll
      for (int kk = 0; kk < 16; ++kk) hreg[kk] = hr[kk * 64];
#pragma unroll
      for (int kk = 0; kk < 16; ++kk) {
        bf16x8 hv = __builtin_bit_cast(bf16x8, hreg[kk]);
        ax0 = __builtin_amdgcn_mfma_f32_16x16x32_bf16(
                __builtin_bit_cast(bf16x8, lA[((16 + kk) * 4 + 0) * 64 + lane]), hv, ax0, 0, 0, 0);
        ax1 = __builtin_amdgcn_mfma_f32_16x16x32_bf16(
                __builtin_bit_cast(bf16x8, lA[((16 + kk) * 4 + 1) * 64 + lane]), hv, ax1, 0, 0, 0);
        ax2 = __builtin_amdgcn_mfma_f32_16x16x32_bf16(
                __builtin_bit_cast(bf16x8, lA[((16 + kk) * 4 + 2) * 64 + lane]), hv, ax2, 0, 0, 0);
        ax3 = __builtin_amdgcn_mfma_f32_16x16x32_bf16(
                __builtin_bit_cast(bf16x8, lA[((16 + kk) * 4 + 3) * 64 + lane]), hv, ax3, 0, 0, 0);
      }
    }

    f32x4 axv[4] = {ax0, ax1, ax2, ax3};
#pragma unroll
    for (int tau = 0; tau < 4; ++tau) {
      float gi = axv[tau][0], gf = axv[tau][1], gg = axv[tau][2], go = axv[tau][3];
      float it = sigm(gi), ft = sigm(gf), ot = sigm(go), gt = tanh_fast(gg);
      c[tau] = ft * c[tau] + it * gt;
      hn[tau] = ot * tanh_fast(c[tau]);
    }

    ushort_t* hw = hbuf + (size_t)((t + 1) & 1) * 32768;
    if (t < SEQ_LEN - 1) {
#pragma unroll
      for (int tau = 0; tau < 4; ++tau) hw[uoff[tau]] = f2bf(hn[tau]);
    }
    __threadfence();
    cg::this_grid().sync();
    __threadfence();
  }

#pragma unroll
  for (int tau = 0; tau < 4; ++tau) {
    out[(size_t)b * 512 + kh[tau]] = hn[tau];
    out[32768 + (size_t)b * 512 + kh[tau]] = c[tau];
  }
}

extern "C" void kernel_launch(void* const* d_in, const int* in_sizes, int n_in,
                              void* d_out, int out_size, void* d_ws, size_t ws_size,
                              hipStream_t stream) {
  const float* x    = (const float*)d_in[0];
  const float* Wi   = (const float*)d_in[1];
  const float* Wh   = (const float*)d_in[2];
  const float* bias = (const float*)d_in[3];
  float* out = (float*)d_out;

  bool fast = (d_ws != nullptr) && (ws_size >= WS_NEED);

  if (fast) {
    const u32x4* xpack = (const u32x4*)d_ws;
    const u32x4* wpack = (const u32x4*)((char*)d_ws + WPACK_OFF);
    ushort_t* hx  = (ushort_t*)((char*)d_ws + HX_OFF);
    uint32* flags = (uint32*)((char*)d_ws + FLG_OFF);

    zero_mem_kernel<<<1, 256, 0, stream>>>((u32x4*)((char*)d_ws + FLG_OFF)); // 4KB flags
    pack_x_kernel<<<16384, 256, 0, stream>>>(x, (u32x4*)d_ws);
    pack_w_kernel<<<8192, 256, 0, stream>>>(Wi, Wh, (ushort_t*)((char*)d_ws + WPACK_OFF));

    lstm_fast<<<dim3(64), dim3(512), 0, stream>>>(
        xpack, wpack, bias, hx, flags, out);
  } else {
    ushort_t* hbuf = (ushort_t*)d_out;   // two 64KB slots inside 256KB d_out

    void* args[] = {(void*)&x, (void*)&Wi, (void*)&Wh, (void*)&bias,
                    (void*)&hbuf, (void*)&out};
    void (*kfn)(const float*, const float*, const float*, const float*,
                ushort_t*, float*) = lstm_slow;
    hipLaunchCooperativeKernel(reinterpret_cast<void*>(kfn), dim3(32), dim3(256),
                               args, 0, stream);
  }
}